// Round 7
// baseline (272.925 us; speedup 1.0000x reference)
//
#include <hip/hip_runtime.h>

// Kuramoto helix network v8: v7 + software-pipelined weight streams.
//  - K B-frags double-buffered in registers (BfA/BfB); layer l+1's loads
//    issued during layer l's steps (grid-limited occupancy -> VGPRs free).
//  - K0 loads issued inside the encoder phase.
//  - per-layer constants (dtcc, dt*omega) preloaded at kernel start.
// Math identical to v7 (same f16 K MFMA dynamics, hi/lo f16 encoder,
// small-angle rotation updates, end wrap).

#define NB 2048
#define NIN 512
#define NOUT 128
#define NOSC 256
#define DTT 0.1f

#define WS_WENC (512*1024)
#define WS_WD   (1024*1024)

typedef _Float16 f16;
typedef _Float16 f16x8 __attribute__((ext_vector_type(8)));
typedef float f32x4 __attribute__((ext_vector_type(4)));

__device__ __forceinline__ float wrapf(float t) {
    return t - 6.28318530717958648f * rintf(t * 0.159154943091895336f);
}

__device__ __forceinline__ void upd1(float aS, float aC, float dtom, float dtcc,
                                     float& th, float& s, float& c) {
    float diff = fmaf(c, aS, -(s * aC));
    float dth  = fmaf(diff, dtcc, dtom);
    th += dth;
    float q  = dth * dth;
    float sd = dth * fmaf(q, -0.166666667f, 1.0f);
    float cd = fmaf(q, fmaf(q, 0.0416666679f, -0.5f), 1.0f);
    float ns = fmaf(s, cd,  c * sd);
    float nc = fmaf(c, cd, -(s * sd));
    s = ns; c = nc;
}

// ---- prep: lay K (f16), W_enc (f16 hi/lo), W_dec (f16) out in frag layout ----
__global__ __launch_bounds__(256) void helix_prep(
    const float* __restrict__ Ks, const float* __restrict__ Wenc,
    const float* __restrict__ Wdec, char* __restrict__ ws)
{
    const int g = blockIdx.x * 256 + threadIdx.x;
    if (g < 32768) {                       // K: [l 4][nt 16][kf 8][ln 64]
        const int ln = g & 63, lg = ln >> 4, lr = ln & 15;
        const int kf = (g >> 6) & 7, nt = (g >> 9) & 15, l = (g >> 13) & 3;
        const float* s = Ks + (((size_t)l * NOSC + nt * 16 + lr) * NOSC + kf * 32 + lg * 8);
        f16x8 o;
        #pragma unroll
        for (int e = 0; e < 8; ++e) o[e] = (f16)s[e];
        *(f16x8*)(ws + (size_t)g * 16) = o;
    } else if (g < 65536) {                // Wenc: [nt 16][kf 16][h 2][ln 64]
        const int q = g - 32768;
        const int ln = q & 63, lg = ln >> 4, lr = ln & 15;
        const int h = (q >> 6) & 1, kf = (q >> 7) & 15, nt = (q >> 11) & 15;
        const float* s = Wenc + ((size_t)(nt * 16 + lr) * NIN + kf * 32 + lg * 8);
        f16x8 o;
        #pragma unroll
        for (int e = 0; e < 8; ++e) {
            float v = s[e];
            f16 hi = (f16)v;
            o[e] = h ? (f16)(v - (float)hi) : hi;
        }
        *(f16x8*)(ws + WS_WENC + (size_t)q * 16) = o;
    } else if (g < 69632) {                // Wdec: [nt 8][kf 8][ln 64]
        const int q = g - 65536;
        const int ln = q & 63, lg = ln >> 4, lr = ln & 15;
        const int kf = (q >> 6) & 7, nt = (q >> 9) & 7;
        const float* s = Wdec + ((size_t)(nt * 16 + lr) * NOSC + kf * 32 + lg * 8);
        f16x8 o;
        #pragma unroll
        for (int e = 0; e < 8; ++e) o[e] = (f16)s[e];
        *(f16x8*)(ws + WS_WD + (size_t)q * 16) = o;
    }
}

__global__ __launch_bounds__(256, 2) void helix8(
    const float* __restrict__ x,
    const float* __restrict__ b_enc,
    const float* __restrict__ omegas,
    const float* __restrict__ Kgl,
    const float* __restrict__ mgl,
    const float* __restrict__ b_dec,
    const char* __restrict__ ws,
    float* __restrict__ out)
{
    // [0,16384): encoder A (16x512 f16) -> dynamics dbuf (2x8KB) -> decoder A
    // [16384,20480): th_lds f32[4][256]
    // [20480,20608): coherence partials [wv 4][r 4][2]
    __shared__ __align__(16) char smem[20736];
    float* th_lds = (float*)(smem + 16384);
    float* coh    = (float*)(smem + 20480);

    const int tid = threadIdx.x;
    const int wv = tid >> 6, ln = tid & 63, lg = ln >> 4, lr = ln & 15;
    const int d  = lr >> 3;
    const int row0 = blockIdx.x * 4;

    float* out_y   = out;
    float* out_th  = out + (size_t)NB * NOUT;
    float* out_coh = out + (size_t)NB * (NOUT + NOSC);

    const int4 zz = make_int4(0, 0, 0, 0);

    // ---- preload all per-layer constants (static indexing only) ----
    float dtccA[4];
    float4 omg4[4];
    #pragma unroll
    for (int l = 0; l < 4; ++l) {
        dtccA[l] = DTT * Kgl[l] * (1.0f / (float)NOSC) * (mgl[l] * 0.5f);
        const float* op = omegas + l * NOSC + 64 * wv + lr;
        omg4[l] = make_float4(DTT * op[0], DTT * op[16], DTT * op[32], DTT * op[48]);
    }

    // ---- P0: x -> encoder-A LDS (hi rows 0-3, lo rows 4-7, zeros 8-15) ----
    {
        const int k0 = ln * 8;
        const float* xp = x + (size_t)(row0 + wv) * NIN + k0;
        float4 v0 = *(const float4*)xp;
        float4 v1 = *(const float4*)(xp + 4);
        float vv[8] = {v0.x, v0.y, v0.z, v0.w, v1.x, v1.y, v1.z, v1.w};
        f16x8 hi, lo;
        #pragma unroll
        for (int e = 0; e < 8; ++e) {
            hi[e] = (f16)vv[e];
            lo[e] = (f16)(vv[e] - (float)hi[e]);
        }
        char* base = smem + (k0 >> 3) * 256;
        *(f16x8*)(base + wv * 16)        = hi;
        *(f16x8*)(base + (wv + 4) * 16)  = lo;
        *(int4*)(base + (wv + 8) * 16)   = zz;
        *(int4*)(base + (wv + 12) * 16)  = zz;
    }
    __syncthreads();

    // ---- K loader (f16 frag layout from ws) ----
    f16x8 BfA[4][8], BfB[4][8];
    auto loadK = [&](int l, f16x8 (&B)[4][8]) {
        #pragma unroll
        for (int t = 0; t < 4; ++t) {
            const char* kb = ws + (size_t)l * 131072 + (size_t)(4 * wv + t) * 8192 + ln * 16;
            #pragma unroll
            for (int kf = 0; kf < 8; ++kf)
                B[t][kf] = *(const f16x8*)(kb + kf * 1024);
        }
    };

    // ---- P1: encoder MFMA ----
    float th[4][2], sv[4][2], cv[4][2];
    {
        f32x4 accH[4] = {{0,0,0,0},{0,0,0,0},{0,0,0,0},{0,0,0,0}};
        f32x4 accL[4] = {{0,0,0,0},{0,0,0,0},{0,0,0,0},{0,0,0,0}};
        const char* aBase = smem + lg * 256 + lr * 16;
        const char* wE0 = ws + WS_WENC + (size_t)(4 * wv + 0) * 32768 + ln * 16;
        const char* wE1 = wE0 + 32768, *wE2 = wE0 + 65536, *wE3 = wE0 + 98304;
        const char* wE[4] = {wE0, wE1, wE2, wE3};
        #pragma unroll 4
        for (int kf = 0; kf < 16; ++kf) {
            f16x8 a = *(const f16x8*)(aBase + kf * 1024);
            #pragma unroll
            for (int t = 0; t < 4; ++t) {
                f16x8 bh = *(const f16x8*)(wE[t] + kf * 2048);
                f16x8 bl = *(const f16x8*)(wE[t] + kf * 2048 + 1024);
                accH[t] = __builtin_amdgcn_mfma_f32_16x16x32_f16(a, bh, accH[t], 0, 0, 0);
                accL[t] = __builtin_amdgcn_mfma_f32_16x16x32_f16(a, bl, accL[t], 0, 0, 0);
            }
        }

        // issue layer-0 K loads now: they stream while the encoder epilogue
        // (shfls, wrap, sincos) and P2 run.
        loadK(0, BfA);

        #pragma unroll
        for (int t = 0; t < 4; ++t) {
            const int ct = 64 * wv + 16 * t + lr;
            const float be = b_enc[ct];
            float tp[4];
            #pragma unroll
            for (int e = 0; e < 4; ++e) {
                float v = accH[t][e] + accL[t][e];
                v += __shfl_xor(v, 16);
                tp[e] = v;
            }
            #pragma unroll
            for (int p = 0; p < 2; ++p) {
                th[t][p] = wrapf(tp[(2 * lg + p) & 3] + be);
                sincosf(th[t][p], &sv[t][p], &cv[t][p]);
            }
        }
    }
    __syncthreads();

    // ---- dynamics addresses (swizzled slots) ----
    int wb[4];
    #pragma unroll
    for (int t = 0; t < 4; ++t)
        wb[t] = (8 * wv + 2 * t + d) * 256 + lg * 64 + (lr & 7) * 2;
    const int pz = d << 5;
    const int rb = lg * 256 + (lr ^ ((lg & 1) << 1)) * 16;

    // ---- P2: zero dynamics-A slots 8..15 in both buffers + prefill buf0 ----
    #pragma unroll
    for (int q = 0; q < 2; ++q) {
        const int id = tid + q * 256;
        *(int4*)(smem + (id >> 8) * 8192 + ((id & 255) >> 3) * 256 + (8 + (id & 7)) * 16) = zz;
    }
    if (lg < 2) {
        #pragma unroll
        for (int t = 0; t < 4; ++t) {
            *(f16*)(smem + wb[t] + (pz ^ 0))  = (f16)sv[t][0];
            *(f16*)(smem + wb[t] + (pz ^ 16)) = (f16)cv[t][0];
            *(f16*)(smem + wb[t] + (pz ^ 32)) = (f16)sv[t][1];
            *(f16*)(smem + wb[t] + (pz ^ 48)) = (f16)cv[t][1];
        }
    }
    __syncthreads();

    // ---- dynamics step ----
    auto STEP = [&](const char* Sb, char* Wb, const f16x8 (&Bc)[4][8],
                    const float4 om, const float dtcc) {
        f16x8 a[8];
        #pragma unroll
        for (int kf = 0; kf < 8; ++kf)
            a[kf] = *(const f16x8*)(Sb + kf * 1024 + rb);
        __builtin_amdgcn_s_setprio(1);
        const float dt_[4] = {om.x, om.y, om.z, om.w};
        #pragma unroll
        for (int t = 0; t < 4; ++t) {
            f32x4 acc = {0.f, 0.f, 0.f, 0.f};
            #pragma unroll
            for (int kf = 0; kf < 8; ++kf)
                acc = __builtin_amdgcn_mfma_f32_16x16x32_f16(a[kf], Bc[t][kf], acc, 0, 0, 0);
            upd1(acc[0], acc[1], dt_[t], dtcc, th[t][0], sv[t][0], cv[t][0]);
            upd1(acc[2], acc[3], dt_[t], dtcc, th[t][1], sv[t][1], cv[t][1]);
            if (lg < 2) {
                *(f16*)(Wb + wb[t] + (pz ^ 0))  = (f16)sv[t][0];
                *(f16*)(Wb + wb[t] + (pz ^ 16)) = (f16)cv[t][0];
                *(f16*)(Wb + wb[t] + (pz ^ 32)) = (f16)sv[t][1];
                *(f16*)(Wb + wb[t] + (pz ^ 48)) = (f16)cv[t][1];
            }
        }
        __builtin_amdgcn_s_setprio(0);
        __syncthreads();
    };

    // layer runner: prefetch next layer's K at double-step 2 (6 steps to land)
    auto runLayer = [&](f16x8 (&Bc)[4][8], f16x8 (&Bn)[4][8], int lNext,
                        const float4 om, const float dtcc) {
        #pragma unroll 1
        for (int p5 = 0; p5 < 5; ++p5) {
            if (p5 == 2 && lNext >= 0) loadK(lNext, Bn);
            STEP(smem,        smem + 8192, Bc, om, dtcc);
            STEP(smem + 8192, smem,        Bc, om, dtcc);
        }
    };

    runLayer(BfA, BfB, 1,  omg4[0], dtccA[0]);
    runLayer(BfB, BfA, 2,  omg4[1], dtccA[1]);
    runLayer(BfA, BfB, 3,  omg4[2], dtccA[2]);
    runLayer(BfB, BfA, -1, omg4[3], dtccA[3]);

    // ---- epilogue ----
    if (lg < 2) {
        #pragma unroll
        for (int t = 0; t < 4; ++t)
            #pragma unroll
            for (int p = 0; p < 2; ++p) {
                const int ct = 64 * wv + 16 * t + lr;
                const int r = 2 * lg + p;
                const float wt = wrapf(th[t][p]);
                th_lds[r * NOSC + ct] = wt;
                *(f16*)(smem + (ct >> 3) * 256 + ((r ^ (d << 1)) * 16) + (lr & 7) * 2) = (f16)wt;
            }
    }
    if (tid < 128)   // zero decoder-A slots 4-7 (8-15 still zero from P2)
        *(int4*)(smem + (tid >> 2) * 256 + (4 + (tid & 3)) * 16) = zz;
    #pragma unroll
    for (int p = 0; p < 2; ++p) {
        float pS = sv[0][p] + sv[1][p] + sv[2][p] + sv[3][p];
        float pC = cv[0][p] + cv[1][p] + cv[2][p] + cv[3][p];
        pS += __shfl_xor(pS, 1); pC += __shfl_xor(pC, 1);
        pS += __shfl_xor(pS, 2); pC += __shfl_xor(pC, 2);
        pS += __shfl_xor(pS, 4); pC += __shfl_xor(pC, 4);
        pS += __shfl_xor(pS, 8); pC += __shfl_xor(pC, 8);
        if (lr == 0 && lg < 2) {
            coh[(wv * 4 + 2 * lg + p) * 2]     = pS;
            coh[(wv * 4 + 2 * lg + p) * 2 + 1] = pC;
        }
    }
    __syncthreads();

    // theta out (coalesced)
    {
        float4 v = *(float4*)(th_lds + tid * 4);
        *(float4*)(out_th + (size_t)row0 * NOSC + tid * 4) = v;
    }
    // coherence
    if (tid < 4) {
        float S = 0.f, C = 0.f;
        #pragma unroll
        for (int w2 = 0; w2 < 4; ++w2) {
            S += coh[(w2 * 4 + tid) * 2];
            C += coh[(w2 * 4 + tid) * 2 + 1];
        }
        S *= (1.0f / (float)NOSC);
        C *= (1.0f / (float)NOSC);
        out_coh[row0 + tid] = sqrtf(S * S + C * C);
    }
    // decoder MFMA: wave wv -> out cols [32wv, 32wv+32)
    {
        f32x4 aD[2] = {{0,0,0,0},{0,0,0,0}};
        #pragma unroll
        for (int kf = 0; kf < 8; ++kf) {
            f16x8 a = *(const f16x8*)(smem + kf * 1024 + rb);
            #pragma unroll
            for (int u = 0; u < 2; ++u) {
                f16x8 bw = *(const f16x8*)(ws + WS_WD + (size_t)(2 * wv + u) * 8192 + kf * 1024 + ln * 16);
                aD[u] = __builtin_amdgcn_mfma_f32_16x16x32_f16(a, bw, aD[u], 0, 0, 0);
            }
        }
        if (lg == 0) {
            #pragma unroll
            for (int u = 0; u < 2; ++u) {
                const int col = (2 * wv + u) * 16 + lr;
                const float bd = b_dec[col];
                #pragma unroll
                for (int e = 0; e < 4; ++e)
                    out_y[(size_t)(row0 + e) * NOUT + col] = aD[u][e] + bd;
            }
        }
    }
}

extern "C" void kernel_launch(void* const* d_in, const int* in_sizes, int n_in,
                              void* d_out, int out_size, void* d_ws, size_t ws_size,
                              hipStream_t stream) {
    const float* x     = (const float*)d_in[0];
    const float* W_enc = (const float*)d_in[1];
    const float* b_enc = (const float*)d_in[2];
    const float* Ks    = (const float*)d_in[3];
    const float* omg   = (const float*)d_in[4];
    const float* Kgl   = (const float*)d_in[5];
    const float* mgl   = (const float*)d_in[6];
    const float* W_dec = (const float*)d_in[7];
    const float* b_dec = (const float*)d_in[8];
    char* ws = (char*)d_ws;

    helix_prep<<<272, 256, 0, stream>>>(Ks, W_enc, W_dec, ws);
    helix8<<<NB / 4, 256, 0, stream>>>(x, b_enc, omg, Kgl, mgl, b_dec, ws, (float*)d_out);
}

// Round 8
// 63.175 us; speedup vs baseline: 4.3202x; 4.3202x over previous
//
#include <hip/hip_runtime.h>

// Kuramoto helix network v9: 8-wave blocks for 4 waves/SIMD occupancy.
// v8 post-mortem: K reg-double-buffer (256 regs) spilled to scratch (574MB
// traffic). v9 reverts to single K buffer and instead splits K across 8
// waves (Bf[2][8] = 64 regs/lane), fitting the 128-reg cap of 4 waves/SIMD:
//   512 thr x 512 blocks, 4 rows/block, 2 blocks/CU, 16 waves/CU.
// All LDS layouts/swizzles = v7 verified (jg = 4wv+2u+d). Math identical.

#define NB 2048
#define NIN 512
#define NOUT 128
#define NOSC 256
#define DTT 0.1f

#define WS_WENC (512*1024)
#define WS_WD   (1024*1024)

typedef _Float16 f16;
typedef _Float16 f16x8 __attribute__((ext_vector_type(8)));
typedef float f32x4 __attribute__((ext_vector_type(4)));

__device__ __forceinline__ float wrapf(float t) {
    return t - 6.28318530717958648f * rintf(t * 0.159154943091895336f);
}

__device__ __forceinline__ void upd1(float aS, float aC, float dtom, float dtcc,
                                     float& th, float& s, float& c) {
    float diff = fmaf(c, aS, -(s * aC));
    float dth  = fmaf(diff, dtcc, dtom);
    th += dth;
    float q  = dth * dth;
    float sd = dth * fmaf(q, -0.166666667f, 1.0f);
    float cd = fmaf(q, fmaf(q, 0.0416666679f, -0.5f), 1.0f);
    float ns = fmaf(s, cd,  c * sd);
    float nc = fmaf(c, cd, -(s * sd));
    s = ns; c = nc;
}

// ---- prep: lay K (f16), W_enc (f16 hi/lo), W_dec (f16) out in frag layout ----
__global__ __launch_bounds__(256) void helix_prep(
    const float* __restrict__ Ks, const float* __restrict__ Wenc,
    const float* __restrict__ Wdec, char* __restrict__ ws)
{
    const int g = blockIdx.x * 256 + threadIdx.x;
    if (g < 32768) {                       // K: [l 4][nt 16][kf 8][ln 64]
        const int ln = g & 63, lg = ln >> 4, lr = ln & 15;
        const int kf = (g >> 6) & 7, nt = (g >> 9) & 15, l = (g >> 13) & 3;
        const float* s = Ks + (((size_t)l * NOSC + nt * 16 + lr) * NOSC + kf * 32 + lg * 8);
        f16x8 o;
        #pragma unroll
        for (int e = 0; e < 8; ++e) o[e] = (f16)s[e];
        *(f16x8*)(ws + (size_t)g * 16) = o;
    } else if (g < 65536) {                // Wenc: [nt 16][kf 16][h 2][ln 64]
        const int q = g - 32768;
        const int ln = q & 63, lg = ln >> 4, lr = ln & 15;
        const int h = (q >> 6) & 1, kf = (q >> 7) & 15, nt = (q >> 11) & 15;
        const float* s = Wenc + ((size_t)(nt * 16 + lr) * NIN + kf * 32 + lg * 8);
        f16x8 o;
        #pragma unroll
        for (int e = 0; e < 8; ++e) {
            float v = s[e];
            f16 hi = (f16)v;
            o[e] = h ? (f16)(v - (float)hi) : hi;
        }
        *(f16x8*)(ws + WS_WENC + (size_t)q * 16) = o;
    } else if (g < 69632) {                // Wdec: [nt 8][kf 8][ln 64]
        const int q = g - 65536;
        const int ln = q & 63, lg = ln >> 4, lr = ln & 15;
        const int kf = (q >> 6) & 7, nt = (q >> 9) & 7;
        const float* s = Wdec + ((size_t)(nt * 16 + lr) * NOSC + kf * 32 + lg * 8);
        f16x8 o;
        #pragma unroll
        for (int e = 0; e < 8; ++e) o[e] = (f16)s[e];
        *(f16x8*)(ws + WS_WD + (size_t)q * 16) = o;
    }
}

__global__ __launch_bounds__(512, 4) void helix9(
    const float* __restrict__ x,
    const float* __restrict__ b_enc,
    const float* __restrict__ omegas,
    const float* __restrict__ Kgl,
    const float* __restrict__ mgl,
    const float* __restrict__ b_dec,
    const char* __restrict__ ws,
    float* __restrict__ out)
{
    // [0,16384): encoder A (16x512 f16) -> dynamics dbuf (2x8KB) -> decoder A
    // [16384,20480): th_lds f32[4][256]
    // [20480,20736): coherence partials [wv 8][r 4][2]
    __shared__ __align__(16) char smem[20736];
    float* th_lds = (float*)(smem + 16384);
    float* coh    = (float*)(smem + 20480);

    const int tid = threadIdx.x;           // 0..511
    const int wv = tid >> 6, ln = tid & 63, lg = ln >> 4, lr = ln & 15;
    const int d  = lr >> 3;
    const int row0 = blockIdx.x * 4;

    float* out_y   = out;
    float* out_th  = out + (size_t)NB * NOUT;
    float* out_coh = out + (size_t)NB * (NOUT + NOSC);

    const int4 zz = make_int4(0, 0, 0, 0);

    // ---- preload per-layer constants (static indexing only) ----
    float dtccA[4];
    float2 omg2[4];
    #pragma unroll
    for (int l = 0; l < 4; ++l) {
        dtccA[l] = DTT * Kgl[l] * (1.0f / (float)NOSC) * (mgl[l] * 0.5f);
        const float* op = omegas + l * NOSC + 32 * wv + lr;
        omg2[l] = make_float2(DTT * op[0], DTT * op[16]);
    }

    // ---- P0: x -> encoder-A LDS (hi rows 0-3, lo 4-7, zeros 8-15) ----
    {
        const int k0 = ln * 8;
        char* base = smem + (k0 >> 3) * 256;
        if (wv < 4) {
            const float* xp = x + (size_t)(row0 + wv) * NIN + k0;
            float4 v0 = *(const float4*)xp;
            float4 v1 = *(const float4*)(xp + 4);
            float vv[8] = {v0.x, v0.y, v0.z, v0.w, v1.x, v1.y, v1.z, v1.w};
            f16x8 hi, lo;
            #pragma unroll
            for (int e = 0; e < 8; ++e) {
                hi[e] = (f16)vv[e];
                lo[e] = (f16)(vv[e] - (float)hi[e]);
            }
            *(f16x8*)(base + wv * 16)       = hi;
            *(f16x8*)(base + (wv + 4) * 16) = lo;
        } else {
            *(int4*)(base + (wv + 4) * 16)  = zz;   // slots 8..11
            *(int4*)(base + (wv + 8) * 16)  = zz;   // slots 12..15
        }
    }
    __syncthreads();

    // ---- K in registers: wave wv owns col-tiles {2wv, 2wv+1} ----
    f16x8 Bf[2][8];
    auto loadK = [&](int l) {
        #pragma unroll
        for (int u = 0; u < 2; ++u) {
            const char* kb = ws + (size_t)l * 131072 + (size_t)(2 * wv + u) * 8192 + ln * 16;
            #pragma unroll
            for (int kf = 0; kf < 8; ++kf)
                Bf[u][kf] = *(const f16x8*)(kb + kf * 1024);
        }
    };

    // ---- P1: encoder MFMA (2 col-tiles per wave) ----
    float th[2][2], sv[2][2], cv[2][2];
    {
        f32x4 accH[2] = {{0,0,0,0},{0,0,0,0}};
        f32x4 accL[2] = {{0,0,0,0},{0,0,0,0}};
        const char* aBase = smem + lg * 256 + lr * 16;
        const char* wE0 = ws + WS_WENC + (size_t)(2 * wv) * 32768 + ln * 16;
        const char* wE1 = wE0 + 32768;
        #pragma unroll 4
        for (int kf = 0; kf < 16; ++kf) {
            f16x8 a = *(const f16x8*)(aBase + kf * 1024);
            f16x8 bh0 = *(const f16x8*)(wE0 + kf * 2048);
            f16x8 bl0 = *(const f16x8*)(wE0 + kf * 2048 + 1024);
            accH[0] = __builtin_amdgcn_mfma_f32_16x16x32_f16(a, bh0, accH[0], 0, 0, 0);
            accL[0] = __builtin_amdgcn_mfma_f32_16x16x32_f16(a, bl0, accL[0], 0, 0, 0);
            f16x8 bh1 = *(const f16x8*)(wE1 + kf * 2048);
            f16x8 bl1 = *(const f16x8*)(wE1 + kf * 2048 + 1024);
            accH[1] = __builtin_amdgcn_mfma_f32_16x16x32_f16(a, bh1, accH[1], 0, 0, 0);
            accL[1] = __builtin_amdgcn_mfma_f32_16x16x32_f16(a, bl1, accL[1], 0, 0, 0);
        }

        // issue layer-0 K loads; they stream under the epilogue + P2
        loadK(0);

        #pragma unroll
        for (int u = 0; u < 2; ++u) {
            const int ct = 32 * wv + 16 * u + lr;
            const float be = b_enc[ct];
            float tp[4];
            #pragma unroll
            for (int e = 0; e < 4; ++e) {
                float v = accH[u][e] + accL[u][e];
                v += __shfl_xor(v, 16);
                tp[e] = v;
            }
            #pragma unroll
            for (int p = 0; p < 2; ++p) {
                th[u][p] = wrapf(tp[(2 * lg + p) & 3] + be);
                sincosf(th[u][p], &sv[u][p], &cv[u][p]);
            }
        }
    }
    __syncthreads();

    // ---- dynamics addresses (v7 swizzle, jg = 4wv+2u+d) ----
    int wb[2];
    #pragma unroll
    for (int u = 0; u < 2; ++u)
        wb[u] = (4 * wv + 2 * u + d) * 256 + lg * 64 + (lr & 7) * 2;
    const int pz = d << 5;
    const int rb = lg * 256 + (lr ^ ((lg & 1) << 1)) * 16;

    // ---- P2: zero dynamics-A slots 8..15 (both buffers) + prefill buf0 ----
    {
        const int buf = tid >> 8, r = (tid & 255) >> 3, sl = 8 + (tid & 7);
        *(int4*)(smem + buf * 8192 + r * 256 + sl * 16) = zz;
    }
    if (lg < 2) {
        #pragma unroll
        for (int u = 0; u < 2; ++u) {
            *(f16*)(smem + wb[u] + (pz ^ 0))  = (f16)sv[u][0];
            *(f16*)(smem + wb[u] + (pz ^ 16)) = (f16)cv[u][0];
            *(f16*)(smem + wb[u] + (pz ^ 32)) = (f16)sv[u][1];
            *(f16*)(smem + wb[u] + (pz ^ 48)) = (f16)cv[u][1];
        }
    }
    __syncthreads();

    // ---- dynamics step: 16 MFMA, 4 upd1, 8 f16 writes per lane ----
    auto STEP = [&](const char* Sb, char* Wb, const float2 om, const float dtcc) {
        f32x4 acc0 = {0.f,0.f,0.f,0.f}, acc1 = {0.f,0.f,0.f,0.f};
        __builtin_amdgcn_s_setprio(1);
        #pragma unroll
        for (int kf = 0; kf < 8; ++kf) {
            f16x8 a = *(const f16x8*)(Sb + kf * 1024 + rb);
            acc0 = __builtin_amdgcn_mfma_f32_16x16x32_f16(a, Bf[0][kf], acc0, 0, 0, 0);
            acc1 = __builtin_amdgcn_mfma_f32_16x16x32_f16(a, Bf[1][kf], acc1, 0, 0, 0);
        }
        upd1(acc0[0], acc0[1], om.x, dtcc, th[0][0], sv[0][0], cv[0][0]);
        upd1(acc0[2], acc0[3], om.x, dtcc, th[0][1], sv[0][1], cv[0][1]);
        upd1(acc1[0], acc1[1], om.y, dtcc, th[1][0], sv[1][0], cv[1][0]);
        upd1(acc1[2], acc1[3], om.y, dtcc, th[1][1], sv[1][1], cv[1][1]);
        if (lg < 2) {
            #pragma unroll
            for (int u = 0; u < 2; ++u) {
                *(f16*)(Wb + wb[u] + (pz ^ 0))  = (f16)sv[u][0];
                *(f16*)(Wb + wb[u] + (pz ^ 16)) = (f16)cv[u][0];
                *(f16*)(Wb + wb[u] + (pz ^ 32)) = (f16)sv[u][1];
                *(f16*)(Wb + wb[u] + (pz ^ 48)) = (f16)cv[u][1];
            }
        }
        __builtin_amdgcn_s_setprio(0);
        __syncthreads();
    };

    auto runLayer = [&](const float2 om, const float cc) {
        #pragma unroll 1
        for (int p5 = 0; p5 < 5; ++p5) {
            STEP(smem,        smem + 8192, om, cc);
            STEP(smem + 8192, smem,        om, cc);
        }
    };

    runLayer(omg2[0], dtccA[0]);
    loadK(1); runLayer(omg2[1], dtccA[1]);
    loadK(2); runLayer(omg2[2], dtccA[2]);
    loadK(3); runLayer(omg2[3], dtccA[3]);

    // ---- epilogue ----
    if (lg < 2) {
        #pragma unroll
        for (int u = 0; u < 2; ++u)
            #pragma unroll
            for (int p = 0; p < 2; ++p) {
                const int ct = 32 * wv + 16 * u + lr;
                const int r = 2 * lg + p;
                const float wt = wrapf(th[u][p]);
                th_lds[r * NOSC + ct] = wt;
                *(f16*)(smem + (ct >> 3) * 256 + ((r ^ (d << 1)) * 16) + (lr & 7) * 2) = (f16)wt;
            }
    }
    if (tid < 128)   // zero decoder-A slots 4-7 (8-15 still zero from P2)
        *(int4*)(smem + (tid >> 2) * 256 + (4 + (tid & 3)) * 16) = zz;
    #pragma unroll
    for (int p = 0; p < 2; ++p) {
        float pS = sv[0][p] + sv[1][p];
        float pC = cv[0][p] + cv[1][p];
        pS += __shfl_xor(pS, 1); pC += __shfl_xor(pC, 1);
        pS += __shfl_xor(pS, 2); pC += __shfl_xor(pC, 2);
        pS += __shfl_xor(pS, 4); pC += __shfl_xor(pC, 4);
        pS += __shfl_xor(pS, 8); pC += __shfl_xor(pC, 8);
        if (lr == 0 && lg < 2) {
            coh[(wv * 4 + 2 * lg + p) * 2]     = pS;
            coh[(wv * 4 + 2 * lg + p) * 2 + 1] = pC;
        }
    }
    __syncthreads();

    // theta out (coalesced)
    if (tid < 256) {
        float4 v = *(float4*)(th_lds + tid * 4);
        *(float4*)(out_th + (size_t)row0 * NOSC + tid * 4) = v;
    }
    // coherence
    if (tid < 4) {
        float S = 0.f, C = 0.f;
        #pragma unroll
        for (int w2 = 0; w2 < 8; ++w2) {
            S += coh[(w2 * 4 + tid) * 2];
            C += coh[(w2 * 4 + tid) * 2 + 1];
        }
        S *= (1.0f / (float)NOSC);
        C *= (1.0f / (float)NOSC);
        out_coh[row0 + tid] = sqrtf(S * S + C * C);
    }
    // decoder MFMA: wave wv -> out cols [16wv, 16wv+16)
    {
        f32x4 aD = {0.f,0.f,0.f,0.f};
        #pragma unroll
        for (int kf = 0; kf < 8; ++kf) {
            f16x8 a = *(const f16x8*)(smem + kf * 1024 + rb);
            f16x8 bw = *(const f16x8*)(ws + WS_WD + (size_t)wv * 8192 + kf * 1024 + ln * 16);
            aD = __builtin_amdgcn_mfma_f32_16x16x32_f16(a, bw, aD, 0, 0, 0);
        }
        if (lg == 0) {
            const int col = 16 * wv + lr;
            const float bd = b_dec[col];
            #pragma unroll
            for (int e = 0; e < 4; ++e)
                out_y[(size_t)(row0 + e) * NOUT + col] = aD[e] + bd;
        }
    }
}

extern "C" void kernel_launch(void* const* d_in, const int* in_sizes, int n_in,
                              void* d_out, int out_size, void* d_ws, size_t ws_size,
                              hipStream_t stream) {
    const float* x     = (const float*)d_in[0];
    const float* W_enc = (const float*)d_in[1];
    const float* b_enc = (const float*)d_in[2];
    const float* Ks    = (const float*)d_in[3];
    const float* omg   = (const float*)d_in[4];
    const float* Kgl   = (const float*)d_in[5];
    const float* mgl   = (const float*)d_in[6];
    const float* W_dec = (const float*)d_in[7];
    const float* b_dec = (const float*)d_in[8];
    char* ws = (char*)d_ws;

    helix_prep<<<272, 256, 0, stream>>>(Ks, W_enc, W_dec, ws);
    helix9<<<NB / 4, 512, 0, stream>>>(x, b_enc, omg, Kgl, mgl, b_dec, ws, (float*)d_out);
}

// Round 9
// 57.396 us; speedup vs baseline: 4.7551x; 1.1007x over previous
//
#include <hip/hip_runtime.h>

// Kuramoto helix network v10 = v9 + two pipe-load cuts:
//  1. Broadcast-zero A rows: lanes lr>=8 (dynamics/encoder) and lr>=4
//     (decoder) read ONE shared zero granule (same-address broadcast,
//     ~free) instead of distinct zero granules -> A-read bank BW halves.
//     Only 16 zero granules (kf*1024+128) initialized once in P0; the big
//     P2/epilogue zero-fills are gone (slots 8-15 never read).
//  2. upd1 rotation (14 dependent VALU) -> th += dth; __sincosf(th,&s,&c)
//     (4 VALU + 2 trans-pipe ops): less VALU, shorter serial chain.
// Skeleton unchanged: 512 thr x 512 blocks, 4 rows/block, 8 waves x 2
// col-tiles, K f16 in regs, 1 barrier/step, LDS dbuf + slot swizzle.

#define NB 2048
#define NIN 512
#define NOUT 128
#define NOSC 256
#define DTT 0.1f

#define WS_WENC (512*1024)
#define WS_WD   (1024*1024)

typedef _Float16 f16;
typedef _Float16 f16x8 __attribute__((ext_vector_type(8)));
typedef float f32x4 __attribute__((ext_vector_type(4)));

__device__ __forceinline__ float wrapf(float t) {
    return t - 6.28318530717958648f * rintf(t * 0.159154943091895336f);
}

// ---- prep: lay K (f16), W_enc (f16 hi/lo), W_dec (f16) out in frag layout ----
__global__ __launch_bounds__(256) void helix_prep(
    const float* __restrict__ Ks, const float* __restrict__ Wenc,
    const float* __restrict__ Wdec, char* __restrict__ ws)
{
    const int g = blockIdx.x * 256 + threadIdx.x;
    if (g < 32768) {                       // K: [l 4][nt 16][kf 8][ln 64]
        const int ln = g & 63, lg = ln >> 4, lr = ln & 15;
        const int kf = (g >> 6) & 7, nt = (g >> 9) & 15, l = (g >> 13) & 3;
        const float* s = Ks + (((size_t)l * NOSC + nt * 16 + lr) * NOSC + kf * 32 + lg * 8);
        f16x8 o;
        #pragma unroll
        for (int e = 0; e < 8; ++e) o[e] = (f16)s[e];
        *(f16x8*)(ws + (size_t)g * 16) = o;
    } else if (g < 65536) {                // Wenc: [nt 16][kf 16][h 2][ln 64]
        const int q = g - 32768;
        const int ln = q & 63, lg = ln >> 4, lr = ln & 15;
        const int h = (q >> 6) & 1, kf = (q >> 7) & 15, nt = (q >> 11) & 15;
        const float* s = Wenc + ((size_t)(nt * 16 + lr) * NIN + kf * 32 + lg * 8);
        f16x8 o;
        #pragma unroll
        for (int e = 0; e < 8; ++e) {
            float v = s[e];
            f16 hi = (f16)v;
            o[e] = h ? (f16)(v - (float)hi) : hi;
        }
        *(f16x8*)(ws + WS_WENC + (size_t)q * 16) = o;
    } else if (g < 69632) {                // Wdec: [nt 8][kf 8][ln 64]
        const int q = g - 65536;
        const int ln = q & 63, lg = ln >> 4, lr = ln & 15;
        const int kf = (q >> 6) & 7, nt = (q >> 9) & 7;
        const float* s = Wdec + ((size_t)(nt * 16 + lr) * NOSC + kf * 32 + lg * 8);
        f16x8 o;
        #pragma unroll
        for (int e = 0; e < 8; ++e) o[e] = (f16)s[e];
        *(f16x8*)(ws + WS_WD + (size_t)q * 16) = o;
    }
}

__global__ __launch_bounds__(512, 4) void helix10(
    const float* __restrict__ x,
    const float* __restrict__ b_enc,
    const float* __restrict__ omegas,
    const float* __restrict__ Kgl,
    const float* __restrict__ mgl,
    const float* __restrict__ b_dec,
    const char* __restrict__ ws,
    float* __restrict__ out)
{
    // [0,16384): encoder A (16x512 f16) -> dynamics dbuf (2x8KB) -> decoder A
    //            (+ 16 broadcast-zero granules at kf*1024+128)
    // [16384,20480): th_lds f32[4][256]
    // [20480,20736): coherence partials [wv 8][r 4][2]
    __shared__ __align__(16) char smem[20736];
    float* th_lds = (float*)(smem + 16384);
    float* coh    = (float*)(smem + 20480);

    const int tid = threadIdx.x;           // 0..511
    const int wv = tid >> 6, ln = tid & 63, lg = ln >> 4, lr = ln & 15;
    const int d  = lr >> 3;
    const int row0 = blockIdx.x * 4;

    float* out_y   = out;
    float* out_th  = out + (size_t)NB * NOUT;
    float* out_coh = out + (size_t)NB * (NOUT + NOSC);

    const int4 zz = make_int4(0, 0, 0, 0);

    // ---- preload per-layer constants (static indexing only) ----
    float dtccA[4];
    float2 omg2[4];
    #pragma unroll
    for (int l = 0; l < 4; ++l) {
        dtccA[l] = DTT * Kgl[l] * (1.0f / (float)NOSC) * (mgl[l] * 0.5f);
        const float* op = omegas + l * NOSC + 32 * wv + lr;
        omg2[l] = make_float2(DTT * op[0], DTT * op[16]);
    }

    // ---- P0: x -> encoder-A LDS (hi rows 0-3, lo 4-7) + zero granules ----
    {
        const int k0 = ln * 8;
        char* base = smem + (k0 >> 3) * 256;
        if (wv < 4) {
            const float* xp = x + (size_t)(row0 + wv) * NIN + k0;
            float4 v0 = *(const float4*)xp;
            float4 v1 = *(const float4*)(xp + 4);
            float vv[8] = {v0.x, v0.y, v0.z, v0.w, v1.x, v1.y, v1.z, v1.w};
            f16x8 hi, lo;
            #pragma unroll
            for (int e = 0; e < 8; ++e) {
                hi[e] = (f16)vv[e];
                lo[e] = (f16)(vv[e] - (float)hi[e]);
            }
            *(f16x8*)(base + wv * 16)       = hi;
            *(f16x8*)(base + (wv + 4) * 16) = lo;
        }
        if (tid < 16)   // broadcast-zero granules: one per kf column
            *(int4*)(smem + tid * 1024 + 128) = zz;
    }
    __syncthreads();

    // ---- K in registers: wave wv owns col-tiles {2wv, 2wv+1} ----
    f16x8 Bf[2][8];
    auto loadK = [&](int l) {
        #pragma unroll
        for (int u = 0; u < 2; ++u) {
            const char* kb = ws + (size_t)l * 131072 + (size_t)(2 * wv + u) * 8192 + ln * 16;
            #pragma unroll
            for (int kf = 0; kf < 8; ++kf)
                Bf[u][kf] = *(const f16x8*)(kb + kf * 1024);
        }
    };

    // ---- P1: encoder MFMA (broadcast-zero for rows 8-15) ----
    float th[2][2], sv[2][2], cv[2][2];
    {
        f32x4 accH[2] = {{0,0,0,0},{0,0,0,0}};
        f32x4 accL[2] = {{0,0,0,0},{0,0,0,0}};
        const char* aBase = smem + ((lr < 8) ? (lg * 256 + lr * 16) : 128);
        const char* wE0 = ws + WS_WENC + (size_t)(2 * wv) * 32768 + ln * 16;
        const char* wE1 = wE0 + 32768;
        #pragma unroll 4
        for (int kf = 0; kf < 16; ++kf) {
            f16x8 a = *(const f16x8*)(aBase + kf * 1024);
            f16x8 bh0 = *(const f16x8*)(wE0 + kf * 2048);
            f16x8 bl0 = *(const f16x8*)(wE0 + kf * 2048 + 1024);
            accH[0] = __builtin_amdgcn_mfma_f32_16x16x32_f16(a, bh0, accH[0], 0, 0, 0);
            accL[0] = __builtin_amdgcn_mfma_f32_16x16x32_f16(a, bl0, accL[0], 0, 0, 0);
            f16x8 bh1 = *(const f16x8*)(wE1 + kf * 2048);
            f16x8 bl1 = *(const f16x8*)(wE1 + kf * 2048 + 1024);
            accH[1] = __builtin_amdgcn_mfma_f32_16x16x32_f16(a, bh1, accH[1], 0, 0, 0);
            accL[1] = __builtin_amdgcn_mfma_f32_16x16x32_f16(a, bl1, accL[1], 0, 0, 0);
        }

        loadK(0);   // layer-0 K streams under the epilogue + P2

        #pragma unroll
        for (int u = 0; u < 2; ++u) {
            const int ct = 32 * wv + 16 * u + lr;
            const float be = b_enc[ct];
            float tp[4];
            #pragma unroll
            for (int e = 0; e < 4; ++e) {
                float v = accH[u][e] + accL[u][e];
                v += __shfl_xor(v, 16);
                tp[e] = v;
            }
            #pragma unroll
            for (int p = 0; p < 2; ++p) {
                th[u][p] = wrapf(tp[(2 * lg + p) & 3] + be);
                __sincosf(th[u][p], &sv[u][p], &cv[u][p]);
            }
        }
    }
    __syncthreads();

    // ---- dynamics addresses (swizzled slots; lr>=8 -> broadcast zeros) ----
    int wb[2];
    #pragma unroll
    for (int u = 0; u < 2; ++u)
        wb[u] = (4 * wv + 2 * u + d) * 256 + lg * 64 + (lr & 7) * 2;
    const int pz = d << 5;
    const int rb = (lr < 8) ? (lg * 256 + (lr ^ ((lg & 1) << 1)) * 16) : 128;

    // ---- P2: prefill buf0 with initial S/C ----
    if (lg < 2) {
        #pragma unroll
        for (int u = 0; u < 2; ++u) {
            *(f16*)(smem + wb[u] + (pz ^ 0))  = (f16)sv[u][0];
            *(f16*)(smem + wb[u] + (pz ^ 16)) = (f16)cv[u][0];
            *(f16*)(smem + wb[u] + (pz ^ 32)) = (f16)sv[u][1];
            *(f16*)(smem + wb[u] + (pz ^ 48)) = (f16)cv[u][1];
        }
    }
    __syncthreads();

    // ---- dynamics step: 8 reads, 16 MFMA, 4 {dth + sincos}, 8 writes ----
    auto STEP = [&](const char* Sb, char* Wb, const float2 om, const float dtcc) {
        f32x4 acc0 = {0.f,0.f,0.f,0.f}, acc1 = {0.f,0.f,0.f,0.f};
        __builtin_amdgcn_s_setprio(1);
        #pragma unroll
        for (int kf = 0; kf < 8; ++kf) {
            f16x8 a = *(const f16x8*)(Sb + kf * 1024 + rb);
            acc0 = __builtin_amdgcn_mfma_f32_16x16x32_f16(a, Bf[0][kf], acc0, 0, 0, 0);
            acc1 = __builtin_amdgcn_mfma_f32_16x16x32_f16(a, Bf[1][kf], acc1, 0, 0, 0);
        }
        #pragma unroll
        for (int p = 0; p < 2; ++p) {
            float diff0 = fmaf(cv[0][p], acc0[2*p], -(sv[0][p] * acc0[2*p+1]));
            th[0][p] += fmaf(diff0, dtcc, om.x);
            __sincosf(th[0][p], &sv[0][p], &cv[0][p]);
            float diff1 = fmaf(cv[1][p], acc1[2*p], -(sv[1][p] * acc1[2*p+1]));
            th[1][p] += fmaf(diff1, dtcc, om.y);
            __sincosf(th[1][p], &sv[1][p], &cv[1][p]);
        }
        if (lg < 2) {
            #pragma unroll
            for (int u = 0; u < 2; ++u) {
                *(f16*)(Wb + wb[u] + (pz ^ 0))  = (f16)sv[u][0];
                *(f16*)(Wb + wb[u] + (pz ^ 16)) = (f16)cv[u][0];
                *(f16*)(Wb + wb[u] + (pz ^ 32)) = (f16)sv[u][1];
                *(f16*)(Wb + wb[u] + (pz ^ 48)) = (f16)cv[u][1];
            }
        }
        __builtin_amdgcn_s_setprio(0);
        __syncthreads();
    };

    auto runLayer = [&](const float2 om, const float cc) {
        #pragma unroll 1
        for (int p5 = 0; p5 < 5; ++p5) {
            STEP(smem,        smem + 8192, om, cc);
            STEP(smem + 8192, smem,        om, cc);
        }
    };

    runLayer(omg2[0], dtccA[0]);
    loadK(1); runLayer(omg2[1], dtccA[1]);
    loadK(2); runLayer(omg2[2], dtccA[2]);
    loadK(3); runLayer(omg2[3], dtccA[3]);

    // ---- epilogue ----
    // wrap; stage th (f32 for out, f16 decoder-A slots 0-3, swizzled)
    if (lg < 2) {
        #pragma unroll
        for (int u = 0; u < 2; ++u)
            #pragma unroll
            for (int p = 0; p < 2; ++p) {
                const int ct = 32 * wv + 16 * u + lr;
                const int r = 2 * lg + p;
                const float wt = wrapf(th[u][p]);
                th_lds[r * NOSC + ct] = wt;
                *(f16*)(smem + (ct >> 3) * 256 + ((r ^ (d << 1)) * 16) + (lr & 7) * 2) = (f16)wt;
            }
    }
    #pragma unroll
    for (int p = 0; p < 2; ++p) {
        float pS = sv[0][p] + sv[1][p];
        float pC = cv[0][p] + cv[1][p];
        pS += __shfl_xor(pS, 1); pC += __shfl_xor(pC, 1);
        pS += __shfl_xor(pS, 2); pC += __shfl_xor(pC, 2);
        pS += __shfl_xor(pS, 4); pC += __shfl_xor(pC, 4);
        pS += __shfl_xor(pS, 8); pC += __shfl_xor(pC, 8);
        if (lr == 0 && lg < 2) {
            coh[(wv * 4 + 2 * lg + p) * 2]     = pS;
            coh[(wv * 4 + 2 * lg + p) * 2 + 1] = pC;
        }
    }
    __syncthreads();

    // theta out (coalesced)
    if (tid < 256) {
        float4 v = *(float4*)(th_lds + tid * 4);
        *(float4*)(out_th + (size_t)row0 * NOSC + tid * 4) = v;
    }
    // coherence
    if (tid < 4) {
        float S = 0.f, C = 0.f;
        #pragma unroll
        for (int w2 = 0; w2 < 8; ++w2) {
            S += coh[(w2 * 4 + tid) * 2];
            C += coh[(w2 * 4 + tid) * 2 + 1];
        }
        S *= (1.0f / (float)NOSC);
        C *= (1.0f / (float)NOSC);
        out_coh[row0 + tid] = sqrtf(S * S + C * C);
    }
    // decoder MFMA: rows 4-15 via broadcast zeros (lr>=4)
    {
        const int rbD = (lr < 4) ? (lg * 256 + (lr ^ ((lg & 1) << 1)) * 16) : 128;
        f32x4 aD = {0.f,0.f,0.f,0.f};
        #pragma unroll
        for (int kf = 0; kf < 8; ++kf) {
            f16x8 a = *(const f16x8*)(smem + kf * 1024 + rbD);
            f16x8 bw = *(const f16x8*)(ws + WS_WD + (size_t)wv * 8192 + kf * 1024 + ln * 16);
            aD = __builtin_amdgcn_mfma_f32_16x16x32_f16(a, bw, aD, 0, 0, 0);
        }
        if (lg == 0) {
            const int col = 16 * wv + lr;
            const float bd = b_dec[col];
            #pragma unroll
            for (int e = 0; e < 4; ++e)
                out_y[(size_t)(row0 + e) * NOUT + col] = aD[e] + bd;
        }
    }
}

extern "C" void kernel_launch(void* const* d_in, const int* in_sizes, int n_in,
                              void* d_out, int out_size, void* d_ws, size_t ws_size,
                              hipStream_t stream) {
    const float* x     = (const float*)d_in[0];
    const float* W_enc = (const float*)d_in[1];
    const float* b_enc = (const float*)d_in[2];
    const float* Ks    = (const float*)d_in[3];
    const float* omg   = (const float*)d_in[4];
    const float* Kgl   = (const float*)d_in[5];
    const float* mgl   = (const float*)d_in[6];
    const float* W_dec = (const float*)d_in[7];
    const float* b_dec = (const float*)d_in[8];
    char* ws = (char*)d_ws;

    helix_prep<<<272, 256, 0, stream>>>(Ks, W_enc, W_dec, ws);
    helix10<<<NB / 4, 512, 0, stream>>>(x, b_enc, omg, Kgl, mgl, b_dec, ws, (float*)d_out);
}

// Round 10
// 41.634 us; speedup vs baseline: 6.5554x; 1.3786x over previous
//
#include <hip/hip_runtime.h>

// Kuramoto helix network v11: full-M restructure.
//  - 1024-thr block (16 waves), 8 batch rows, grid 256 (1 block/CU).
//  - Dynamics A = 16 REAL rows [S r, C r interleaved], r=0..7: MFMA/CU/step
//    halves vs v10 (no zero-row padding). Wave wv owns col-tile wv (16 cols);
//    K regs Bf[8] = 32 VGPR.
//  - Encoder full-M too: A rows [x_hi r, x_lo r] interleaved -> hi/lo combine
//    is a local reg add (no shfl); weight traffic halves (one block/CU).
//  - Same verified frag layouts + slot swizzle (slot = m ^ 2*granule_parity).
// LDS: [0,16K) enc-A 16x512 f16 -> dyn dbuf 2x8K; [16K,24K) th_lds f32[8][256];
//      [24K,25.6K) coherence partials [16 wv][8 r] S,C.

#define NB 2048
#define NIN 512
#define NOUT 128
#define NOSC 256
#define DTT 0.1f

#define WS_WENC (512*1024)
#define WS_WD   (1024*1024)

typedef _Float16 f16;
typedef _Float16 f16x4 __attribute__((ext_vector_type(4)));
typedef _Float16 f16x8 __attribute__((ext_vector_type(8)));
typedef float f32x4 __attribute__((ext_vector_type(4)));

__device__ __forceinline__ float wrapf(float t) {
    return t - 6.28318530717958648f * rintf(t * 0.159154943091895336f);
}

// ---- prep: lay K (f16), W_enc (f16 hi/lo), W_dec (f16) out in frag layout ----
__global__ __launch_bounds__(256) void helix_prep(
    const float* __restrict__ Ks, const float* __restrict__ Wenc,
    const float* __restrict__ Wdec, char* __restrict__ ws)
{
    const int g = blockIdx.x * 256 + threadIdx.x;
    if (g < 32768) {                       // K: [l 4][nt 16][kf 8][ln 64]
        const int ln = g & 63, lg = ln >> 4, lr = ln & 15;
        const int kf = (g >> 6) & 7, nt = (g >> 9) & 15, l = (g >> 13) & 3;
        const float* s = Ks + (((size_t)l * NOSC + nt * 16 + lr) * NOSC + kf * 32 + lg * 8);
        f16x8 o;
        #pragma unroll
        for (int e = 0; e < 8; ++e) o[e] = (f16)s[e];
        *(f16x8*)(ws + (size_t)g * 16) = o;
    } else if (g < 65536) {                // Wenc: [nt 16][kf 16][h 2][ln 64]
        const int q = g - 32768;
        const int ln = q & 63, lg = ln >> 4, lr = ln & 15;
        const int h = (q >> 6) & 1, kf = (q >> 7) & 15, nt = (q >> 11) & 15;
        const float* s = Wenc + ((size_t)(nt * 16 + lr) * NIN + kf * 32 + lg * 8);
        f16x8 o;
        #pragma unroll
        for (int e = 0; e < 8; ++e) {
            float v = s[e];
            f16 hi = (f16)v;
            o[e] = h ? (f16)(v - (float)hi) : hi;
        }
        *(f16x8*)(ws + WS_WENC + (size_t)q * 16) = o;
    } else if (g < 69632) {                // Wdec: [nt 8][kf 8][ln 64]
        const int q = g - 65536;
        const int ln = q & 63, lg = ln >> 4, lr = ln & 15;
        const int kf = (q >> 6) & 7, nt = (q >> 9) & 7;
        const float* s = Wdec + ((size_t)(nt * 16 + lr) * NOSC + kf * 32 + lg * 8);
        f16x8 o;
        #pragma unroll
        for (int e = 0; e < 8; ++e) o[e] = (f16)s[e];
        *(f16x8*)(ws + WS_WD + (size_t)q * 16) = o;
    }
}

__global__ __launch_bounds__(1024, 4) void helix11(
    const float* __restrict__ x,
    const float* __restrict__ b_enc,
    const float* __restrict__ omegas,
    const float* __restrict__ Kgl,
    const float* __restrict__ mgl,
    const float* __restrict__ b_dec,
    const char* __restrict__ ws,
    float* __restrict__ out)
{
    __shared__ __align__(16) char smem[25600];
    float* th_lds = (float*)(smem + 16384);
    float* cohPS  = (float*)(smem + 24576);           // [16 wv][8 r]
    float* cohPC  = (float*)(smem + 25088);

    const int tid = threadIdx.x;           // 0..1023
    const int wv = tid >> 6, ln = tid & 63, lg = ln >> 4, lr = ln & 15;
    const int d  = lr >> 3;
    const int row0 = blockIdx.x * 8;
    const int jb  = 16 * wv + lr;          // this lane's oscillator column

    float* out_y   = out;
    float* out_th  = out + (size_t)NB * NOUT;
    float* out_coh = out + (size_t)NB * (NOUT + NOSC);

    const int4 zz = make_int4(0, 0, 0, 0);

    // ---- per-layer constants (all static, held in regs) ----
    float dtccA[4], omL[4];
    #pragma unroll
    for (int l = 0; l < 4; ++l) {
        dtccA[l] = DTT * Kgl[l] * (1.0f / (float)NOSC) * (mgl[l] * 0.5f);
        omL[l]   = DTT * omegas[l * NOSC + jb];
    }

    // ---- P0: x -> encoder-A LDS, rows m = 2r+h (hi/lo interleaved) ----
    {
        const int r  = tid >> 7;            // 0..7
        const int j0 = (tid & 127) << 2;    // 4 f32 per thread
        float4 v = *(const float4*)(x + (size_t)(row0 + r) * NIN + j0);
        float vv[4] = {v.x, v.y, v.z, v.w};
        f16x4 hi, lo;
        #pragma unroll
        for (int e = 0; e < 4; ++e) {
            hi[e] = (f16)vv[e];
            lo[e] = (f16)(vv[e] - (float)hi[e]);
        }
        char* base = smem + (j0 >> 5) * 1024 + ((j0 >> 3) & 3) * 256 + (j0 & 7) * 2;
        *(f16x4*)(base + (2 * r) * 16)     = hi;
        *(f16x4*)(base + (2 * r + 1) * 16) = lo;
    }
    __syncthreads();

    // ---- K loader: wave wv owns col-tile wv ----
    f16x8 Bf[8];
    auto loadK = [&](const int l) {
        const char* kb = ws + (size_t)l * 131072 + (size_t)wv * 8192 + ln * 16;
        #pragma unroll
        for (int kf = 0; kf < 8; ++kf)
            Bf[kf] = *(const f16x8*)(kb + kf * 1024);
    };

    // ---- P1: encoder MFMA (full M; hi/lo combine local) ----
    float th[2], sv[2], cv[2];
    {
        f32x4 accH = {0,0,0,0}, accL = {0,0,0,0};
        const char* aBase = smem + lg * 256 + lr * 16;
        const char* wE = ws + WS_WENC + (size_t)wv * 32768 + ln * 16;
        #pragma unroll 4
        for (int kf = 0; kf < 16; ++kf) {
            f16x8 a  = *(const f16x8*)(aBase + kf * 1024);
            f16x8 bh = *(const f16x8*)(wE + kf * 2048);
            f16x8 bl = *(const f16x8*)(wE + kf * 2048 + 1024);
            accH = __builtin_amdgcn_mfma_f32_16x16x32_f16(a, bh, accH, 0, 0, 0);
            accL = __builtin_amdgcn_mfma_f32_16x16x32_f16(a, bl, accL, 0, 0, 0);
        }
        loadK(0);   // layer-0 K streams under the epilogue + prefill
        const float be = b_enc[jb];
        #pragma unroll
        for (int p = 0; p < 2; ++p) {
            // row r = 2lg+p: hi-part in acc[2p], lo-part in acc[2p+1]
            float tval = accH[2*p] + accH[2*p+1] + accL[2*p] + accL[2*p+1] + be;
            th[p] = wrapf(tval);
            __sincosf(th[p], &sv[p], &cv[p]);
        }
    }
    __syncthreads();   // all encoder A-reads done before dynamics overwrites

    // ---- dynamics addresses ----
    // element (m, j) at byte (j>>5)*1024 + ((j>>3)&3)*256 + (m^(2*((j>>3)&1)))*16 + (j&7)*2
    const int rb = lg * 256 + (lr ^ ((lg & 1) << 1)) * 16;   // read: row lr, gcol lg
    const int wbase = (jb >> 5) * 1024 + ((jb >> 3) & 3) * 256 + (lr & 7) * 2;
    const int wz0 = wbase + (((4 * lg + 0) ^ (d << 1)) << 4);
    const int wz1 = wbase + (((4 * lg + 1) ^ (d << 1)) << 4);
    const int wz2 = wbase + (((4 * lg + 2) ^ (d << 1)) << 4);
    const int wz3 = wbase + (((4 * lg + 3) ^ (d << 1)) << 4);

    // ---- prefill buf0 with initial S/C (every lane: 4 f16) ----
    *(f16*)(smem + wz0) = (f16)sv[0];
    *(f16*)(smem + wz1) = (f16)cv[0];
    *(f16*)(smem + wz2) = (f16)sv[1];
    *(f16*)(smem + wz3) = (f16)cv[1];
    __syncthreads();

    // ---- dynamics step: 8 reads, 8 MFMA, 2 {fma,fma,sincos}, 4 writes ----
    auto STEP = [&](const char* Sb, char* Wb, const float om, const float cc) {
        f32x4 acc = {0.f, 0.f, 0.f, 0.f};
        __builtin_amdgcn_s_setprio(1);
        #pragma unroll
        for (int kf = 0; kf < 8; ++kf) {
            f16x8 a = *(const f16x8*)(Sb + kf * 1024 + rb);
            acc = __builtin_amdgcn_mfma_f32_16x16x32_f16(a, Bf[kf], acc, 0, 0, 0);
        }
        #pragma unroll
        for (int p = 0; p < 2; ++p) {
            float diff = fmaf(cv[p], acc[2*p], -(sv[p] * acc[2*p+1]));
            th[p] += fmaf(diff, cc, om);
            __sincosf(th[p], &sv[p], &cv[p]);
        }
        *(f16*)(Wb + wz0) = (f16)sv[0];
        *(f16*)(Wb + wz1) = (f16)cv[0];
        *(f16*)(Wb + wz2) = (f16)sv[1];
        *(f16*)(Wb + wz3) = (f16)cv[1];
        __builtin_amdgcn_s_setprio(0);
        __syncthreads();
    };

    auto runLayer = [&](const float om, const float cc) {
        #pragma unroll 1
        for (int p5 = 0; p5 < 5; ++p5) {
            STEP(smem,        smem + 8192, om, cc);
            STEP(smem + 8192, smem,        om, cc);
        }
    };

    runLayer(omL[0], dtccA[0]);
    loadK(1); runLayer(omL[1], dtccA[1]);
    loadK(2); runLayer(omL[2], dtccA[2]);
    loadK(3); runLayer(omL[3], dtccA[3]);

    // ---- epilogue ----
    // wrap; stage th into th_lds (f32) + decoder-A (f16, slot=r, unswizzled)
    {
        const int dbase = (jb >> 5) * 1024 + ((jb >> 3) & 3) * 256 + (lr & 7) * 2;
        #pragma unroll
        for (int p = 0; p < 2; ++p) {
            const float wt = wrapf(th[p]);
            th_lds[(2 * lg + p) * NOSC + jb] = wt;
            *(f16*)(smem + dbase + (2 * lg + p) * 16) = (f16)wt;
        }
    }
    // coherence partials: reduce over lr within each lg group
    #pragma unroll
    for (int p = 0; p < 2; ++p) {
        float pS = sv[p], pC = cv[p];
        pS += __shfl_xor(pS, 1); pC += __shfl_xor(pC, 1);
        pS += __shfl_xor(pS, 2); pC += __shfl_xor(pC, 2);
        pS += __shfl_xor(pS, 4); pC += __shfl_xor(pC, 4);
        pS += __shfl_xor(pS, 8); pC += __shfl_xor(pC, 8);
        if (lr == 0) {
            cohPS[wv * 8 + 2 * lg + p] = pS;
            cohPC[wv * 8 + 2 * lg + p] = pC;
        }
    }
    __syncthreads();

    if (tid < 8)   // zero granule (slot 8, gcol 0) per kf for decoder rows 8-15
        *(int4*)(smem + tid * 1024 + 128) = zz;
    if (tid < 512) {   // theta out, coalesced (8 rows x 256 contiguous)
        float4 v = ((const float4*)th_lds)[tid];
        *(float4*)(out_th + (size_t)row0 * NOSC + tid * 4) = v;
    }
    if (tid < 8) {     // coherence
        float S = 0.f, C = 0.f;
        #pragma unroll
        for (int w2 = 0; w2 < 16; ++w2) {
            S += cohPS[w2 * 8 + tid];
            C += cohPC[w2 * 8 + tid];
        }
        S *= (1.0f / (float)NOSC);
        C *= (1.0f / (float)NOSC);
        out_coh[row0 + tid] = sqrtf(S * S + C * C);
    }
    __syncthreads();

    // decoder MFMA: waves 0-7 -> out col-tile wv (16 cols); rows 8-15 zero
    if (wv < 8) {
        const int rbD = (lr < 8) ? (lg * 256 + lr * 16) : 128;
        f32x4 aD = {0.f, 0.f, 0.f, 0.f};
        #pragma unroll
        for (int kf = 0; kf < 8; ++kf) {
            f16x8 a  = *(const f16x8*)(smem + kf * 1024 + rbD);
            f16x8 bw = *(const f16x8*)(ws + WS_WD + (size_t)wv * 8192 + kf * 1024 + ln * 16);
            aD = __builtin_amdgcn_mfma_f32_16x16x32_f16(a, bw, aD, 0, 0, 0);
        }
        if (lg < 2) {
            const int col = 16 * wv + lr;
            const float bd = b_dec[col];
            #pragma unroll
            for (int e = 0; e < 4; ++e)
                out_y[(size_t)(row0 + 4 * lg + e) * NOUT + col] = aD[e] + bd;
        }
    }
}

extern "C" void kernel_launch(void* const* d_in, const int* in_sizes, int n_in,
                              void* d_out, int out_size, void* d_ws, size_t ws_size,
                              hipStream_t stream) {
    const float* x     = (const float*)d_in[0];
    const float* W_enc = (const float*)d_in[1];
    const float* b_enc = (const float*)d_in[2];
    const float* Ks    = (const float*)d_in[3];
    const float* omg   = (const float*)d_in[4];
    const float* Kgl   = (const float*)d_in[5];
    const float* mgl   = (const float*)d_in[6];
    const float* W_dec = (const float*)d_in[7];
    const float* b_dec = (const float*)d_in[8];
    char* ws = (char*)d_ws;

    helix_prep<<<272, 256, 0, stream>>>(Ks, W_enc, W_dec, ws);
    helix11<<<NB / 8, 1024, 0, stream>>>(x, b_enc, omg, Kgl, mgl, b_dec, ws, (float*)d_out);
}